// Round 11
// baseline (276.935 us; speedup 1.0000x reference)
//
#include <hip/hip_runtime.h>

#define EPS_DIR 1e-15f
#define EPS_W   1e-5f
#define NEAR_MIN 0.05f

// ---------------------------------------------------------------------------
// Tm1=127, n=128 specialized: 8 lanes/ray; coalesced staging; UNIFORM
// per-sample binary search over a sigma-swizzled LDS CDF; float4 stores.
//
// Evidence trail:
//  r5  (94.9us, best): uniform searches win, but 28M bank-conflict cycles
//      (concurrent probes at 16g -> banks {0,16}) + scattered-load TA.
//  r8  (190us): scattered stores/loads -> VMEM address-issue bound.
//  r9  (112us): staging+quads fine, but leader/FOLLOWER while-loops are
//      wave-divergent (cost = wave-max, not mean) -> slower than r5.
// This round: r9's memory pattern + r5's uniform compute + bank fixes:
//  - CDF entry e stored at slot sigma(e)=e+(e>>4), table stride 137
//    (9 mod 32): mid-step probe sets {16,48,80,112}->{17,19,21,23} etc.
//    spread banks; step-64 broadcasts de-aliased across tables by 9*rw.
//  - sample assignment j=32i+4g: concurrent final probes ~4g+32i spread
//    all 32 banks; float4 store inst = contiguous 128B per ray.
//  - no __syncthreads: buffers are wave-private (same-wave DS is in-order);
//    a compiler memory fence orders the staging-region reuse.
// ---------------------------------------------------------------------------
__global__ __launch_bounds__(256) void nerf_sample_pdf_127_128(
    const float* __restrict__ rays_o,
    const float* __restrict__ rays_d,
    const float* __restrict__ weights,
    const int*   __restrict__ bound_p,
    float*       __restrict__ out,
    int R)
{
    const int t    = threadIdx.x;
    const int lane = t & 63;
    const int wv   = t >> 6;           // wave in block (0..3)
    const int g    = t & 7;            // lane within 8-lane ray group
    const int rw   = lane >> 3;        // ray within wave (0..7)
    const int ray  = blockIdx.x * 32 + (t >> 3);
    const bool valid = (ray < R);
    const int rayc = valid ? ray : (R - 1);

    // Per-wave buffer. Phase A: raw rows at stride 127 ([0,1016)).
    // Phase C reuses it as 8 sigma-swizzled CDF tables at stride 137
    // (slots sigma(e)=e+(e>>4), e in [0,128], max slot 137*7+136=1095).
    __shared__ float buf_s[4][1096];   // 17536 B/block
    float* __restrict__ wbuf = buf_s[wv];

    // ---- phase A: stage this wave's 8 weight rows, fully coalesced ----
    {
        const int ray0 = blockIdx.x * 32 + wv * 8;
        const size_t gbase = (size_t)ray0 * 127;
        const size_t total = (size_t)R * 127;
#pragma unroll
        for (int k = 0; k < 16; ++k) {
            const int idx = 64 * k + lane;          // 0..1023 (1016..1023: junk,
            const size_t gi = gbase + (size_t)idx;  //  never read back)
            wbuf[idx] = (gi < total) ? weights[gi] : 0.0f;
        }
    }

    // ---- phase B: lane pulls its 16 weights (row rw, cols 16g..16g+15) ----
    const int i0 = g << 4;
    float w[16];
#pragma unroll
    for (int k = 0; k < 16; ++k) {
        const float rv = wbuf[127 * rw + i0 + k];
        w[k] = (i0 + k < 127) ? rv + EPS_W : 0.0f;  // mask phantom 128th weight
    }

    float local = w[0];
#pragma unroll
    for (int k = 1; k < 16; ++k) local += w[k];

    // ---- 8-lane xor-butterfly: exclusive prefix + group total ----
    float prefix = 0.0f, val = local;
#pragma unroll
    for (int k = 1; k < 8; k <<= 1) {
        const float y = __shfl_xor(val, k, 8);
        if (g & k) prefix += y;
        val += y;                       // ends as group total
    }
    const float rtot = __builtin_amdgcn_rcpf(val);

    // Compiler fence: keep phase-B reads before phase-C writes (region reuse).
    // HW: same-wave DS ops are processed in order; no block barrier needed
    // (each wave touches only its private buf_s[wv]).
    asm volatile("" ::: "memory");

    // ---- phase C: build sigma-swizzled cdf table (stride 137) ----
    float* __restrict__ cdf = wbuf + 137 * rw;
    if (g == 0) cdf[0] = 0.0f;          // sigma(0) = 0
    {
        float run = prefix;
#pragma unroll
        for (int k = 0; k < 16; ++k) {
            run += w[k];
            const int e = i0 + k + 1;           // 1..128 (g=7,k=15 -> 128,
            cdf[e + (e >> 4)] = run * rtot;     //  dup of 127: h-read safe)
        }
    }

    // ---- near/far cube intersection (8-lane redundant per ray) ----
    const float b = (float)bound_p[0];
    float nearv = -3.4e38f, farv = 3.4e38f;
#pragma unroll
    for (int k = 0; k < 3; ++k) {
        const float o = rays_o[(size_t)rayc * 3 + k];
        const float d = rays_d[(size_t)rayc * 3 + k] + EPS_DIR;
        const float r = __builtin_amdgcn_rcpf(d);
        const float t0 = (-b - o) * r;
        const float t1 = ( b - o) * r;
        nearv = fmaxf(nearv, fminf(t0, t1));
        farv  = fminf(farv,  fmaxf(t0, t1));
    }
    nearv = fmaxf(nearv, NEAR_MIN);
    const float scale = (farv - nearv) * (1.0f / 127.0f);

    // ---- phase D: 16 samples/lane, j = 32i + 4g + s, UNIFORM 7-step
    //      searchsorted-right per sample (no data-dependent loops) ----
    float* __restrict__ orow = out + (size_t)ray * 128;
    const float inv_n = 1.0f / 128.0f;      // u = (j+0.5)/128 exact dyadics

#pragma unroll
    for (int i = 0; i < 4; ++i) {
        const int jb = 32 * i + 4 * g;
        float z0, z1, z2, z3;
#pragma unroll
        for (int s = 0; s < 4; ++s) {
            const float u = ((float)(jb + s) + 0.5f) * inv_n;
            int p = 0; float v = 0.0f;
#pragma unroll
            for (int step = 64; step >= 1; step >>= 1) {
                const int e = p + step;             // <= 127 by invariant
                const float c = cdf[e + (e >> 4)];
                if (c <= u) { p = e; v = c; }
            }
            const int ea = p + 1;                   // <= 128 (slot exists)
            const float h   = cdf[ea + (ea >> 4)];
            const float dnm = h - v;
            const float rd  = (dnm < EPS_W) ? 1.0f : __builtin_amdgcn_rcpf(dnm);
            const float z   = fmaf((float)p + (u - v) * rd, scale, nearv);
            if      (s == 0) z0 = z;
            else if (s == 1) z1 = z;
            else if (s == 2) z2 = z;
            else             z3 = z;
        }
        if (valid) {
            *reinterpret_cast<float4*>(orow + jb) = make_float4(z0, z1, z2, z3);
        }
    }
}

// ---------------------------------------------------------------------------
// Generic fallback (round-3 kernel, verified correct): wave-per-ray gather.
// Used only if the shape is not (Tm1=127, n=128).
// ---------------------------------------------------------------------------
__global__ __launch_bounds__(256) void nerf_sample_pdf_generic(
    const float* __restrict__ rays_o,
    const float* __restrict__ rays_d,
    const float* __restrict__ weights,
    const int*   __restrict__ bound_p,
    float*       __restrict__ out,
    int R, int Tm1, int n)
{
    const int lane = threadIdx.x & 63;
    const int wid  = threadIdx.x >> 6;
    int ray = blockIdx.x * 4 + wid;
    const bool valid = (ray < R);
    if (!valid) ray = R - 1;

    __shared__ float cdf_s[4][132];
    float* __restrict__ cdf = cdf_s[wid];

    const float* __restrict__ wrow = weights + (size_t)ray * Tm1;
    const int i0 = 2 * lane, i1 = 2 * lane + 1;
    float w0 = (i0 < Tm1) ? (wrow[i0] + EPS_W) : 0.0f;
    float w1 = (i1 < Tm1) ? (wrow[i1] + EPS_W) : 0.0f;

    float S = w0 + w1;
#pragma unroll
    for (int off = 1; off < 64; off <<= 1) {
        float y = __shfl_up(S, off, 64);
        if (lane >= off) S += y;
    }
    const float total = __shfl(S, 63, 64);
    const float rinv  = __builtin_amdgcn_rcpf(total);
    float prevS = __shfl_up(S, 1, 64);
    if (lane == 0) prevS = 0.0f;

    cdf[i0] = prevS * rinv;
    cdf[i1] = (prevS + w0) * rinv;
    __syncthreads();

    const float b = (float)bound_p[0];
    float nearv = -3.4e38f, farv = 3.4e38f;
#pragma unroll
    for (int k = 0; k < 3; ++k) {
        float o = rays_o[(size_t)ray * 3 + k];
        float d = rays_d[(size_t)ray * 3 + k] + EPS_DIR;
        float r = __builtin_amdgcn_rcpf(d);
        float t0 = (-b - o) * r;
        float t1 = ( b - o) * r;
        nearv = fmaxf(nearv, fminf(t0, t1));
        farv  = fminf(farv,  fmaxf(t0, t1));
    }
    nearv = fmaxf(nearv, NEAR_MIN);
    const float scale = (farv - nearv) * __builtin_amdgcn_rcpf((float)Tm1);
    const float inv_n = 1.0f / (float)n;

    float* __restrict__ orow = out + (size_t)ray * n;

    for (int base = 0; base < n; base += 128) {
        const int j = base + 2 * lane;
        if (j >= n) break;
        const float u0 = ((float)j + 0.5f) * inv_n;
        const float u1 = u0 + inv_n;

        int   p0 = 0,   p1 = 0;
        float v0 = 0.f, v1 = 0.f;
#pragma unroll
        for (int step = 64; step >= 1; step >>= 1) {
            if (p0 + step <= Tm1) {
                const float c0 = cdf[p0 + step];
                if (c0 <= u0) { p0 += step; v0 = c0; }
            }
            if (p1 + step <= Tm1) {
                const float c1 = cdf[p1 + step];
                if (c1 <= u1) { p1 += step; v1 = c1; }
            }
        }
        const int a0 = (p0 < Tm1) ? p0 + 1 : Tm1;
        const int a1 = (p1 < Tm1) ? p1 + 1 : Tm1;
        const float h0 = cdf[a0];
        const float h1 = cdf[a1];
        const float d0 = h0 - v0;
        const float d1 = h1 - v1;
        const float t0 = (u0 - v0) * ((d0 < EPS_W) ? 1.0f : __builtin_amdgcn_rcpf(d0));
        const float t1 = (u1 - v1) * ((d1 < EPS_W) ? 1.0f : __builtin_amdgcn_rcpf(d1));
        const float z0 = fmaf(t0, (float)(a0 - p0) * scale, fmaf((float)p0, scale, nearv));
        const float z1 = fmaf(t1, (float)(a1 - p1) * scale, fmaf((float)p1, scale, nearv));

        if (valid) {
            if (j + 1 < n) {
                *reinterpret_cast<float2*>(orow + j) = make_float2(z0, z1);
            } else {
                orow[j] = z0;
            }
        }
    }
}

extern "C" void kernel_launch(void* const* d_in, const int* in_sizes, int n_in,
                              void* d_out, int out_size, void* d_ws, size_t ws_size,
                              hipStream_t stream) {
    const float* rays_o  = (const float*)d_in[0];
    const float* rays_d  = (const float*)d_in[1];
    const float* weights = (const float*)d_in[2];
    const int*   bound_p = (const int*)d_in[3];
    float*       out     = (float*)d_out;

    const int R   = in_sizes[0] / 3;       // 262144 rays
    const int Tm1 = in_sizes[2] / R;       // 127 weights per ray
    const int n   = out_size / R;          // 128 samples per ray

    if (Tm1 == 127 && n == 128) {
        dim3 grid((R + 31) / 32), block(256);   // 32 rays/block, 8 lanes/ray
        nerf_sample_pdf_127_128<<<grid, block, 0, stream>>>(
            rays_o, rays_d, weights, bound_p, out, R);
    } else {
        dim3 grid((R + 3) / 4), block(256);
        nerf_sample_pdf_generic<<<grid, block, 0, stream>>>(
            rays_o, rays_d, weights, bound_p, out, R, Tm1, n);
    }
}